// Round 1
// baseline (562.806 us; speedup 1.0000x reference)
//
#include <hip/hip_runtime.h>
#include <hip/hip_bf16.h>
#include <math.h>

// Problem constants
#define BATCH 64
#define LDIM  256
#define HDIM  1024
#define DDIM  1024
#define BAND  16
#define MNZ   33          // 2*BAND+1
#define NN    (DDIM*MNZ)  // 33792
#define RTILE 64          // k3 rows per block
#define LSTR  34          // k3 LDS row stride (pad 33->34)

typedef float  v4f    __attribute__((ext_vector_type(4)));
typedef float  f32x4  __attribute__((ext_vector_type(4)));
typedef short  bf16x8 __attribute__((ext_vector_type(8)));

static __device__ __forceinline__ unsigned short f2bf(float x) {
    union { float f; unsigned int u; } a; a.f = x;
    unsigned int r = a.u + 0x7fffu + ((a.u >> 16) & 1u);
    return (unsigned short)(r >> 16);
}

// ---------------------------------------------------------------------------
// K1: h = gelu(z @ W1 + b1) -> bf16, row-major hb[b][k]   (unchanged; ~4 us)
// ---------------------------------------------------------------------------
__global__ __launch_bounds__(256) void k1_h(const float* __restrict__ z,
                                            const float* __restrict__ W1,
                                            const float* __restrict__ b1,
                                            unsigned short* __restrict__ hb) {
    __shared__ float zs[LDIM];
    const int t = threadIdx.x;
    const int b = blockIdx.y;
    const int j = blockIdx.x * 256 + t;
    zs[t] = z[b * LDIM + t];
    __syncthreads();
    float acc = b1[j];
#pragma unroll 8
    for (int l = 0; l < LDIM; ++l)
        acc = fmaf(zs[l], W1[l * HDIM + j], acc);
    float g = 0.5f * acc * (1.0f + erff(acc * 0.70710678118654752f));
    hb[(size_t)b * HDIM + j] = f2bf(g);
}

// ---------------------------------------------------------------------------
// K2 (restructured): v = h @ W2 + b2 via bf16 MFMA 16x16x32, NO K-split.
// Grid: NN/16 = 2112 blocks x 64 threads (1 wave). Each wave owns 16 cols,
// full K=1024 (32 steps of K=32), writes final v once (8.65 MB vs 34.6 MB).
// B-fragment loaded DIRECTLY from W2: lane(kq,nl) reads W2[k0+kq*8+j][c0+nl]
// -> per instr 4 aligned 64B segments, zero overfetch, no LDS/barrier at all.
// Depth-2 pipeline on both W2 and hb loads.
// ---------------------------------------------------------------------------
__global__ __launch_bounds__(64) void k2_v(const float* __restrict__ W2,
                                           const float* __restrict__ b2,
                                           const unsigned short* __restrict__ hb,
                                           float* __restrict__ v) {
    const int lane = threadIdx.x;        // 0..63
    const int c0   = blockIdx.x * 16;
    const int kq   = lane >> 4;          // 0..3
    const int nl   = lane & 15;          // 0..15

    f32x4 acc[4];
#pragma unroll
    for (int mt = 0; mt < 4; ++mt) acc[mt] = (f32x4){0.f, 0.f, 0.f, 0.f};

    // B loads: row (s*32 + kq*8 + j), col (c0 + nl)
    const float* __restrict__ wp =
        W2 + (size_t)(kq * 8) * NN + (size_t)c0 + nl;
    // A loads: hb[(mt*16 + nl)*HDIM + s*32 + kq*8]
    const unsigned short* __restrict__ hp =
        hb + (size_t)nl * HDIM + kq * 8;

    auto loadW = [&](int s, float (&w)[8]) {
#pragma unroll
        for (int j = 0; j < 8; ++j)
            w[j] = wp[(size_t)(s * 32 + j) * NN];
    };
    auto loadA = [&](int s, bf16x8 (&a)[4]) {
#pragma unroll
        for (int mt = 0; mt < 4; ++mt)
            a[mt] = *(const bf16x8*)(hp + (size_t)(mt * 16) * HDIM + s * 32);
    };
    auto consume = [&](float (&w)[8], bf16x8 (&a)[4]) {
        bf16x8 bfr;
#pragma unroll
        for (int j = 0; j < 8; ++j) bfr[j] = (short)f2bf(w[j]);
#pragma unroll
        for (int mt = 0; mt < 4; ++mt)
            acc[mt] = __builtin_amdgcn_mfma_f32_16x16x32_bf16(
                a[mt], bfr, acc[mt], 0, 0, 0);
    };

    float  wA[8], wB[8];
    bf16x8 aA[4], aB[4];
    loadW(0, wA); loadA(0, aA);

#pragma unroll 1
    for (int sp = 0; sp < 32; sp += 2) {
        loadW(sp + 1, wB); loadA(sp + 1, aB);
        consume(wA, aA);
        const int sn = (sp + 2 < 32) ? (sp + 2) : 31;  // last pair: redundant reload
        loadW(sn, wA); loadA(sn, aA);
        consume(wB, aB);
    }

    // epilogue: C[m = mt*16 + kq*4 + r][n = c0 + nl], bias added once here
    const float bias = b2[c0 + nl];
    float* __restrict__ vo = v + (size_t)c0 + nl;
#pragma unroll
    for (int mt = 0; mt < 4; ++mt)
#pragma unroll
        for (int r = 0; r < 4; ++r)
            vo[(size_t)(mt * 16 + kq * 4 + r) * NN] = acc[mt][r] + bias;
}

// ---------------------------------------------------------------------------
// K3: block = (batch b, 64-row tile). Stage v rows [i0-16, i0+80) into LDS
// (coalesced, single slice now), then 64 output rows of float4 NT stores.
// ---------------------------------------------------------------------------
__global__ __launch_bounds__(256) void k3_out(const float* __restrict__ v,
                                              float* __restrict__ out) {
    const int tid  = threadIdx.x;
    const int tile = blockIdx.x & (DDIM / RTILE - 1);
    const int b    = blockIdx.x / (DDIM / RTILE);
    const int i0 = tile * RTILE;
    const int js = (i0 >= BAND) ? (i0 - BAND) : 0;
    const int je = (i0 + RTILE + BAND <= DDIM) ? (i0 + RTILE + BAND) : DDIM;
    const int nelem = (je - js) * MNZ;                   // <= 3168

    __shared__ float ls[(RTILE + 2 * BAND) * LSTR];      // 12.75 KB

    const float* __restrict__ vb = v + (size_t)b * NN + (size_t)js * MNZ;
    for (int idx = tid; idx < nelem; idx += 256) {
        const int r = idx / MNZ;
        const int m = idx - r * MNZ;
        ls[r * LSTR + m] = vb[idx];
    }
    __syncthreads();

    const int j0 = tid * 4;
#pragma unroll 2
    for (int r = 0; r < RTILE; ++r) {
        const int i = i0 + r;
        v4f res = (v4f){0.f, 0.f, 0.f, 0.f};
        if (j0 + 3 >= i - BAND && j0 <= i + BAND) {
            const int lo_i = (i > BAND) ? (i - BAND) : 0;
#pragma unroll
            for (int c = 0; c < 4; ++c) {
                const int j = j0 + c;
                const int d = j - i;
                float x = 0.0f;
                if (d >= -BAND && d <= BAND) {
                    const int lo_j = (j > BAND) ? (j - BAND) : 0;
                    x = 0.5f * (ls[(i - js) * LSTR + (j - lo_i)] +
                                ls[(j - js) * LSTR + (i - lo_j)]);
                    if (d == 0) x += 1.0f;
                }
                res[c] = x;
            }
        }
        v4f* dst = ((v4f*)out) + ((size_t)b * DDIM + i) * (DDIM / 4) + tid;
        __builtin_nontemporal_store(res, dst);
    }
}

// ---------------------------------------------------------------------------
// DIAGNOSTIC this round: k2 and k3 are each launched TWICE (idempotent,
// bit-identical results). dur = K1 + 2*K2 + 2*K3 + OH. Next round drops the
// doubles; the delta isolates K2+K3 vs any fixed overhead inside dur_us.
// ---------------------------------------------------------------------------
extern "C" void kernel_launch(void* const* d_in, const int* in_sizes, int n_in,
                              void* d_out, int out_size, void* d_ws, size_t ws_size,
                              hipStream_t stream) {
    const float* z  = (const float*)d_in[0];
    const float* W1 = (const float*)d_in[2];
    const float* b1 = (const float*)d_in[3];
    const float* W2 = (const float*)d_in[4];
    const float* b2 = (const float*)d_in[5];

    unsigned short* hb = (unsigned short*)d_ws;          // 64x1024 bf16 (128 KB)
    float* v = (float*)((char*)d_ws + (size_t)BATCH * HDIM * sizeof(unsigned short));
    float* out = (float*)d_out;

    k1_h  <<<dim3(4, 64), 256, 0, stream>>>(z, W1, b1, hb);
    k2_v  <<<dim3(NN / 16), 64, 0, stream>>>(W2, b2, hb, v);
    k2_v  <<<dim3(NN / 16), 64, 0, stream>>>(W2, b2, hb, v);
    k3_out<<<dim3(BATCH * (DDIM / RTILE)), 256, 0, stream>>>(v, out);
    k3_out<<<dim3(BATCH * (DDIM / RTILE)), 256, 0, stream>>>(v, out);
}